// Round 10
// baseline (962.806 us; speedup 1.0000x reference)
//
#include <hip/hip_runtime.h>

#define B_ 128
#define T_ 512
#define D_ 512
#define H_ 64
#define N3 192   // 3*H

#if __has_builtin(__builtin_amdgcn_rcpf)
#define RCP(x) __builtin_amdgcn_rcpf(x)
#else
#define RCP(x) (1.0f / (x))
#endif

__device__ __forceinline__ float sigm_f(float x) {
  return RCP(1.0f + __expf(-x));
}
__device__ __forceinline__ float tanh_f(float x) {
  float e = __expf(-2.0f * fabsf(x));
  float t = (1.0f - e) * RCP(1.0f + e);
  return copysignf(t, x);
}

// 8-lane sum over lanes jj*8+g (g=0..7) entirely on the VALU via DPP:
// xor1 = quad_perm[1,0,3,2]=0xB1, xor2 = quad_perm[2,3,0,1]=0x4E,
// xor4 = row_half_mirror = 0x141.
template <int CTRL>
__device__ __forceinline__ float dpp_add(float v) {
  int t = __builtin_amdgcn_update_dpp(0, __float_as_int(v), CTRL, 0xF, 0xF, true);
  return v + __int_as_float(t);
}
__device__ __forceinline__ float red8(float v) {
  v = dpp_add<0xB1>(v);
  v = dpp_add<0x4E>(v);
  v = dpp_add<0x141>(v);
  return v;
}

__device__ __forceinline__ float dot8(float4 wa, float4 wb, float4 ha, float4 hb) {
  // two independent chains for ILP
  float s0 = wa.x * ha.x;
  float s1 = wa.y * ha.y;
  s0 = fmaf(wa.z, ha.z, s0);
  s1 = fmaf(wa.w, ha.w, s1);
  s0 = fmaf(wb.x, hb.x, s0);
  s1 = fmaf(wb.y, hb.y, s1);
  s0 = fmaf(wb.z, hb.z, s0);
  s1 = fmaf(wb.w, hb.w, s1);
  return s0 + s1;
}

// ---------------- pass 1: gi0 = x @ W0ih^T + b0ih, plus act[t] flags ----------------
__global__ __launch_bounds__(256) void gemm_kernel(
    const float* __restrict__ x,     // [B,T,D]
    const float* __restrict__ w0ih,  // [N3,D]
    const float* __restrict__ b0ih,  // [N3]
    float* __restrict__ gi0,         // [B,Tc,N3]
    int* __restrict__ act,           // [T]
    int t0, int Tc) {
  __shared__ float Xs[64][33];
  __shared__ float Ws[64][33];
  __shared__ unsigned char sflag[64];

  int tid = threadIdx.x;
  int tpc = Tc >> 6;
  int b  = blockIdx.x / tpc;
  int tt = blockIdx.x % tpc;
  int c0 = blockIdx.y * 64;

  int tx = tid & 15, ty = tid >> 4;
  int r1  = tid >> 3;   // [0,32)
  int kc1 = tid & 7;    // [0,8)

  const float* xbase = x + ((size_t)b * T_ + t0 + tt * 64) * D_;
  const float* wbase = w0ih + (size_t)c0 * D_;

  float acc[4][4];
#pragma unroll
  for (int i = 0; i < 4; i++)
#pragma unroll
    for (int q = 0; q < 4; q++) acc[i][q] = 0.0f;

  bool f1 = false, f2 = false;

  for (int kt = 0; kt < D_ / 32; ++kt) {
    float4 va = *(const float4*)&xbase[(size_t)r1 * D_ + kt * 32 + kc1 * 4];
    float4 vb = *(const float4*)&xbase[(size_t)(r1 + 32) * D_ + kt * 32 + kc1 * 4];
    float4 wa = *(const float4*)&wbase[(size_t)r1 * D_ + kt * 32 + kc1 * 4];
    float4 wb = *(const float4*)&wbase[(size_t)(r1 + 32) * D_ + kt * 32 + kc1 * 4];
    f1 |= (va.x != 0.0f) | (va.y != 0.0f) | (va.z != 0.0f) | (va.w != 0.0f);
    f2 |= (vb.x != 0.0f) | (vb.y != 0.0f) | (vb.z != 0.0f) | (vb.w != 0.0f);
    __syncthreads();
    Xs[r1][kc1 * 4 + 0] = va.x; Xs[r1][kc1 * 4 + 1] = va.y;
    Xs[r1][kc1 * 4 + 2] = va.z; Xs[r1][kc1 * 4 + 3] = va.w;
    Xs[r1 + 32][kc1 * 4 + 0] = vb.x; Xs[r1 + 32][kc1 * 4 + 1] = vb.y;
    Xs[r1 + 32][kc1 * 4 + 2] = vb.z; Xs[r1 + 32][kc1 * 4 + 3] = vb.w;
    Ws[r1][kc1 * 4 + 0] = wa.x; Ws[r1][kc1 * 4 + 1] = wa.y;
    Ws[r1][kc1 * 4 + 2] = wa.z; Ws[r1][kc1 * 4 + 3] = wa.w;
    Ws[r1 + 32][kc1 * 4 + 0] = wb.x; Ws[r1 + 32][kc1 * 4 + 1] = wb.y;
    Ws[r1 + 32][kc1 * 4 + 2] = wb.z; Ws[r1 + 32][kc1 * 4 + 3] = wb.w;
    __syncthreads();
#pragma unroll
    for (int k = 0; k < 32; ++k) {
      float a_[4], b_[4];
#pragma unroll
      for (int i = 0; i < 4; i++) a_[i] = Xs[ty * 4 + i][k];
#pragma unroll
      for (int q = 0; q < 4; q++) b_[q] = Ws[tx * 4 + q][k];
#pragma unroll
      for (int i = 0; i < 4; i++)
#pragma unroll
        for (int q = 0; q < 4; q++) acc[i][q] = fmaf(a_[i], b_[q], acc[i][q]);
    }
  }

  float4 bias = *(const float4*)&b0ih[c0 + tx * 4];
#pragma unroll
  for (int i = 0; i < 4; i++) {
    int tloc = tt * 64 + ty * 4 + i;
    float4 o;
    o.x = acc[i][0] + bias.x;
    o.y = acc[i][1] + bias.y;
    o.z = acc[i][2] + bias.z;
    o.w = acc[i][3] + bias.w;
    *(float4*)&gi0[((size_t)b * Tc + tloc) * N3 + c0 + tx * 4] = o;
  }

  if (tid < 64) sflag[tid] = 0;
  __syncthreads();
  if (f1) sflag[r1] = 1;
  if (f2) sflag[r1 + 32] = 1;
  __syncthreads();
  if (tid < 64 && sflag[tid]) act[t0 + tt * 64 + tid] = 1;
}

// ---------------- pass 2: sequential scan, one WG (512 thr) per batch row ----------------
// W0hh/W1hh/W2hh live in LDS f32 (s_w, 147KB), XOR-SWIZZLED: physical 16B
// chunk index = c ^ (row & 7). Without this, rows are 256B (≡0 mod 32 banks)
// and for fixed g all 8 jj-lanes read the same bank quad -> 8-way conflict;
// round-9 measured SQ_LDS_BANK_CONFLICT=3.8e7 and scan sat at the 2.94x
// conflict-degraded LDS-BW floor (737us). With the swizzle the 8 jj-lanes
// cover all 8 bank quads (g vs g+4 is 2-way = free).
// W1ih/W2ih (48 floats) + 15 biases stay in VGPRs (fits the ~96-reg budget
// the allocator grants; rounds 4/6/8 showed bigger plans spill).
// Thread (jj = tid>>3, g = tid&7) owns segment [8g,8g+8) of rows
// {jj, jj+64, jj+128}. DPP reduce over g; 2 barriers/step.
// Hoisting discipline (round-5 race lesson): phase-0 may read only s_h[0][cur]
// and s_h[1][cur]; s_h[2][cur]'s dot stays in layer 2.
__global__ __launch_bounds__(512, 2) void scan_kernel(
    const float* __restrict__ gi0,   // [B,Tc,N3]
    const float* __restrict__ w0hh, const float* __restrict__ w1ih,
    const float* __restrict__ w1hh, const float* __restrict__ w2ih,
    const float* __restrict__ w2hh,
    const float* __restrict__ b0hh, const float* __restrict__ b1ih,
    const float* __restrict__ b1hh, const float* __restrict__ b2ih,
    const float* __restrict__ b2hh,
    const int* __restrict__ act,     // [T]
    float* __restrict__ hstate,      // [3,B,H]
    float* __restrict__ out,         // [B,T,H]
    int t0, int Tc) {
  const int b   = blockIdx.x;
  const int tid = threadIdx.x;
  const int jj  = tid >> 3;   // [0,64) hidden unit
  const int g   = tid & 7;    // [0,8) segment

  __shared__ __align__(16) float4 s_w[3][192][16]; // 0=W0hh,1=W1hh,2=W2hh, swizzled
  __shared__ __align__(16) float s_h[3][2][H_];    // [layer][parity][unit]
  __shared__ __align__(16) float s_out[32][H_];
  __shared__ int s_act[T_];

  // ---- one-time: fill s_w from global, applying the chunk swizzle ----
  {
    const float* wsrc[3] = {w0hh, w1hh, w2hh};
    for (int i = tid; i < 3 * 192 * 16; i += 512) {
      int m = i / 3072;
      int rem = i - m * 3072;
      int row = rem >> 4;        // [0,192)
      int c = rem & 15;          // 16B chunk within row
      s_w[m][row][c ^ (row & 7)] = ((const float4*)wsrc[m])[rem];
    }
  }

  // swizzled chunk indices for this thread's reads (row & 7 == jj & 7)
  const int cA = (2 * g) ^ (jj & 7);
  const int cB = (2 * g + 1) ^ (jj & 7);

  // ---- register-resident: W1ih, W2ih segments + all 15 biases ----
  float4 wih[2][3][2];   // [mat: 0=W1ih, 1=W2ih][gate r][half]
  {
    const float* ip[2] = {w1ih, w2ih};
#pragma unroll
    for (int m = 0; m < 2; m++)
#pragma unroll
      for (int r = 0; r < 3; r++) {
        const float* src = ip[m] + (size_t)(jj + 64 * r) * H_ + 8 * g;
        wih[m][r][0] = *(const float4*)src;
        wih[m][r][1] = *(const float4*)(src + 4);
      }
  }
  float bs[5][3];        // m: 0=b0hh, 1=b1ih, 2=b1hh, 3=b2ih, 4=b2hh
  {
    const float* bp[5] = {b0hh, b1ih, b1hh, b2ih, b2hh};
#pragma unroll
    for (int m = 0; m < 5; m++)
#pragma unroll
      for (int r = 0; r < 3; r++) bs[m][r] = bp[m][jj + 64 * r];
  }

  // ---- h state: register copy (per jj, replicated over g) + LDS copy ----
  float h0, h1, h2;
  if (t0 == 0) {
    h0 = 0.0f; h1 = 0.0f; h2 = 0.0f;
  } else {
    h0 = hstate[0 * B_ * H_ + b * H_ + jj];
    h1 = hstate[1 * B_ * H_ + b * H_ + jj];
    h2 = hstate[2 * B_ * H_ + b * H_ + jj];
  }
  if (tid < H_) {
    s_h[0][0][tid] = (t0 == 0) ? 0.0f : hstate[0 * B_ * H_ + b * H_ + tid];
    s_h[1][0][tid] = (t0 == 0) ? 0.0f : hstate[1 * B_ * H_ + b * H_ + tid];
    s_h[2][0][tid] = (t0 == 0) ? 0.0f : hstate[2 * B_ * H_ + b * H_ + tid];
  }
  for (int i = tid; i < Tc; i += 512) s_act[i] = act[t0 + i];
  __syncthreads();

  const float* gibase = gi0 + (size_t)b * Tc * N3;
  int cur = 0;
  float giR = gibase[jj], giZ = gibase[jj + 64], giN = gibase[jj + 128];

  // weight-from-LDS helper: matrix m2 (s_w index), gate r -> two float4
#define LDSW(m2, rr, wa, wb)                                            \
  {                                                                     \
    const float4* rowp_ = s_w[m2][jj + 64 * (rr)];                      \
    wa = rowp_[cA];                                                     \
    wb = rowp_[cB];                                                     \
  }

  for (int t = 0; t < Tc; ++t) {
    // prefetch next step's gi
    int tn = (t + 1 < Tc) ? t + 1 : t;
    const float* gin = gibase + (size_t)tn * N3;
    float nR = gin[jj], nZ = gin[jj + 64], nN = gin[jj + 128];

    const bool a = (s_act[t] != 0);

    // ---- phase 0: hh-dots for layers 0 and 1 (both barrier-protected) ----
    const float4* hp0 = (const float4*)s_h[0][cur];
    const float4* hp1 = (const float4*)s_h[1][cur];
    float4 ha = hp0[2 * g], hb = hp0[2 * g + 1];
    float4 c0v = hp1[2 * g], c1v = hp1[2 * g + 1];
    float4 wa, wb;
    LDSW(0, 0, wa, wb); float dR = red8(dot8(wa, wb, ha, hb)) + bs[0][0];
    LDSW(0, 1, wa, wb); float dZ = red8(dot8(wa, wb, ha, hb)) + bs[0][1];
    LDSW(0, 2, wa, wb); float dN = red8(dot8(wa, wb, ha, hb)) + bs[0][2];
    LDSW(1, 0, wa, wb); float hR1 = red8(dot8(wa, wb, c0v, c1v)) + bs[2][0];
    LDSW(1, 1, wa, wb); float hZ1 = red8(dot8(wa, wb, c0v, c1v)) + bs[2][1];
    LDSW(1, 2, wa, wb); float hN1 = red8(dot8(wa, wb, c0v, c1v)) + bs[2][2];

    // ---- gate 0 ----
    {
      float r = sigm_f(giR + dR);
      float z = sigm_f(giZ + dZ);
      float n = tanh_f(giN + r * dN);
      float hn = (1.0f - z) * n + z * h0;
      h0 = a ? hn : h0;
    }
    if (g == 0) s_h[0][cur ^ 1][jj] = h0;
    __syncthreads();

    // ---- layer 1: gi = W1ih @ h0new (registers) ; gate 1 ----
    {
      const float4* hq0 = (const float4*)s_h[0][cur ^ 1];
      float4 a0 = hq0[2 * g], a1 = hq0[2 * g + 1];
      float iR = red8(dot8(wih[0][0][0], wih[0][0][1], a0, a1)) + bs[1][0];
      float iZ = red8(dot8(wih[0][1][0], wih[0][1][1], a0, a1)) + bs[1][1];
      float iN = red8(dot8(wih[0][2][0], wih[0][2][1], a0, a1)) + bs[1][2];
      float r = sigm_f(iR + hR1);
      float z = sigm_f(iZ + hZ1);
      float n = tanh_f(iN + r * hN1);
      float hn = (1.0f - z) * n + z * h1;
      h1 = a ? hn : h1;
    }
    if (g == 0) s_h[1][cur ^ 1][jj] = h1;
    __syncthreads();

    // ---- layer 2: gi = W2ih @ h1new (registers) ; gh = W2hh @ h2 (LDS; safe
    //      here: two barriers since s_h[2][cur] was written) ; gate 2 ----
    {
      const float4* hq1 = (const float4*)s_h[1][cur ^ 1];
      const float4* hq2 = (const float4*)s_h[2][cur];
      float4 e0 = hq1[2 * g], e1 = hq1[2 * g + 1];
      float4 f0v = hq2[2 * g], f1v = hq2[2 * g + 1];
      float jR = red8(dot8(wih[1][0][0], wih[1][0][1], e0, e1)) + bs[3][0];
      float jZ = red8(dot8(wih[1][1][0], wih[1][1][1], e0, e1)) + bs[3][1];
      float jN = red8(dot8(wih[1][2][0], wih[1][2][1], e0, e1)) + bs[3][2];
      LDSW(2, 0, wa, wb); float kR = red8(dot8(wa, wb, f0v, f1v)) + bs[4][0];
      LDSW(2, 1, wa, wb); float kZ = red8(dot8(wa, wb, f0v, f1v)) + bs[4][1];
      LDSW(2, 2, wa, wb); float kN = red8(dot8(wa, wb, f0v, f1v)) + bs[4][2];
      float r = sigm_f(jR + kR);
      float z = sigm_f(jZ + kZ);
      float n = tanh_f(jN + r * kN);
      float hn = (1.0f - z) * n + z * h2;
      h2 = a ? hn : h2;
    }
    if (g == 0) {
      s_h[2][cur ^ 1][jj] = h2;
      s_out[t & 31][jj] = a ? h2 : 0.0f;
    }
    // no barrier needed: s_h[2][cur^1] is next read in layer 2 of step t+1
    // (behind two barriers); s_h[0/1] writes are barrier-protected above.
    cur ^= 1;
    giR = nR; giZ = nZ; giN = nN;

    if ((t & 31) == 31) {            // coalesced output flush (Tc % 32 == 0)
      __syncthreads();
      int row = tid >> 4, c4 = (tid & 15) * 4;
      *(float4*)&out[((size_t)b * T_ + t0 + (t - 31) + row) * H_ + c4] =
          *(const float4*)&s_out[row][c4];
      // next s_out write happens after the next step's barriers -> safe
    }
  }
#undef LDSW

  if (g == 0) {
    hstate[0 * B_ * H_ + b * H_ + jj] = h0;
    hstate[1 * B_ * H_ + b * H_ + jj] = h1;
    hstate[2 * B_ * H_ + b * H_ + jj] = h2;
  }
}

extern "C" void kernel_launch(void* const* d_in, const int* in_sizes, int n_in,
                              void* d_out, int out_size, void* d_ws, size_t ws_size,
                              hipStream_t stream) {
  const float* x    = (const float*)d_in[0];
  const float* w0ih = (const float*)d_in[1];
  const float* w0hh = (const float*)d_in[2];
  const float* b0ih = (const float*)d_in[3];
  const float* b0hh = (const float*)d_in[4];
  const float* w1ih = (const float*)d_in[5];
  const float* w1hh = (const float*)d_in[6];
  const float* b1ih = (const float*)d_in[7];
  const float* b1hh = (const float*)d_in[8];
  const float* w2ih = (const float*)d_in[9];
  const float* w2hh = (const float*)d_in[10];
  const float* b2ih = (const float*)d_in[11];
  const float* b2hh = (const float*)d_in[12];
  float* out = (float*)d_out;

  char* p = (char*)d_ws;
  int* act      = (int*)p;    p += 4096;
  float* hstate = (float*)p;  p += (size_t)3 * B_ * H_ * 4;
  size_t fixed = (size_t)(p - (char*)d_ws);

  int Tc = T_;
  while (Tc > 64 && fixed + (size_t)B_ * Tc * N3 * 4 > ws_size) Tc >>= 1;
  float* gi0 = (float*)p;

  hipMemsetAsync(act, 0, T_ * sizeof(int), stream);
  for (int t0 = 0; t0 < T_; t0 += Tc) {
    gemm_kernel<<<dim3(B_ * (Tc / 64), 3), 256, 0, stream>>>(
        x, w0ih, b0ih, gi0, act, t0, Tc);
    scan_kernel<<<B_, 512, 0, stream>>>(
        gi0, w0hh, w1ih, w1hh, w2ih, w2hh,
        b0hh, b1ih, b1hh, b2ih, b2hh, act, hstate, out, t0, Tc);
  }
}

// Round 11
// 871.517 us; speedup vs baseline: 1.1047x; 1.1047x over previous
//
#include <hip/hip_runtime.h>

#define B_ 128
#define T_ 512
#define D_ 512
#define H_ 64
#define N3 192   // 3*H

#if __has_builtin(__builtin_amdgcn_rcpf)
#define RCP(x) __builtin_amdgcn_rcpf(x)
#else
#define RCP(x) (1.0f / (x))
#endif

typedef _Float16 h2v __attribute__((ext_vector_type(2)));

__device__ __forceinline__ float sigm_f(float x) {
  return RCP(1.0f + __expf(-x));
}
__device__ __forceinline__ float tanh_f(float x) {
  float e = __expf(-2.0f * fabsf(x));
  float t = (1.0f - e) * RCP(1.0f + e);
  return copysignf(t, x);
}

// 8-lane sum over lanes jj*8+g (g=0..7) entirely on the VALU via DPP:
// xor1 = quad_perm[1,0,3,2]=0xB1, xor2 = quad_perm[2,3,0,1]=0x4E,
// xor4 = row_half_mirror = 0x141.
template <int CTRL>
__device__ __forceinline__ float dpp_add(float v) {
  int t = __builtin_amdgcn_update_dpp(0, __float_as_int(v), CTRL, 0xF, 0xF, true);
  return v + __int_as_float(t);
}
__device__ __forceinline__ float red8(float v) {
  v = dpp_add<0xB1>(v);
  v = dpp_add<0x4E>(v);
  v = dpp_add<0x141>(v);
  return v;
}

// 8-elem dot: packed-f16 weights (4 dwords) x packed-f16 h (4 dwords),
// f32 accumulation via v_dot2_f32_f16 (two chains for ILP).
__device__ __forceinline__ float dot8pk(const int* w, const h2v* h) {
  float s0 = __builtin_amdgcn_fdot2(__builtin_bit_cast(h2v, w[0]), h[0], 0.0f, false);
  float s1 = __builtin_amdgcn_fdot2(__builtin_bit_cast(h2v, w[1]), h[1], 0.0f, false);
  s0 = __builtin_amdgcn_fdot2(__builtin_bit_cast(h2v, w[2]), h[2], s0, false);
  s1 = __builtin_amdgcn_fdot2(__builtin_bit_cast(h2v, w[3]), h[3], s1, false);
  return s0 + s1;
}

#define KEEP(x) asm volatile("" : "+v"(x))

// ---------------- pass 1: gi0 = x @ W0ih^T + b0ih, plus act[t] flags ----------------
__global__ __launch_bounds__(256) void gemm_kernel(
    const float* __restrict__ x,     // [B,T,D]
    const float* __restrict__ w0ih,  // [N3,D]
    const float* __restrict__ b0ih,  // [N3]
    float* __restrict__ gi0,         // [B,Tc,N3]
    int* __restrict__ act,           // [T]
    int t0, int Tc) {
  __shared__ float Xs[64][33];
  __shared__ float Ws[64][33];
  __shared__ unsigned char sflag[64];

  int tid = threadIdx.x;
  int tpc = Tc >> 6;
  int b  = blockIdx.x / tpc;
  int tt = blockIdx.x % tpc;
  int c0 = blockIdx.y * 64;

  int tx = tid & 15, ty = tid >> 4;
  int r1  = tid >> 3;   // [0,32)
  int kc1 = tid & 7;    // [0,8)

  const float* xbase = x + ((size_t)b * T_ + t0 + tt * 64) * D_;
  const float* wbase = w0ih + (size_t)c0 * D_;

  float acc[4][4];
#pragma unroll
  for (int i = 0; i < 4; i++)
#pragma unroll
    for (int q = 0; q < 4; q++) acc[i][q] = 0.0f;

  bool f1 = false, f2 = false;

  for (int kt = 0; kt < D_ / 32; ++kt) {
    float4 va = *(const float4*)&xbase[(size_t)r1 * D_ + kt * 32 + kc1 * 4];
    float4 vb = *(const float4*)&xbase[(size_t)(r1 + 32) * D_ + kt * 32 + kc1 * 4];
    float4 wa = *(const float4*)&wbase[(size_t)r1 * D_ + kt * 32 + kc1 * 4];
    float4 wb = *(const float4*)&wbase[(size_t)(r1 + 32) * D_ + kt * 32 + kc1 * 4];
    f1 |= (va.x != 0.0f) | (va.y != 0.0f) | (va.z != 0.0f) | (va.w != 0.0f);
    f2 |= (vb.x != 0.0f) | (vb.y != 0.0f) | (vb.z != 0.0f) | (vb.w != 0.0f);
    __syncthreads();
    Xs[r1][kc1 * 4 + 0] = va.x; Xs[r1][kc1 * 4 + 1] = va.y;
    Xs[r1][kc1 * 4 + 2] = va.z; Xs[r1][kc1 * 4 + 3] = va.w;
    Xs[r1 + 32][kc1 * 4 + 0] = vb.x; Xs[r1 + 32][kc1 * 4 + 1] = vb.y;
    Xs[r1 + 32][kc1 * 4 + 2] = vb.z; Xs[r1 + 32][kc1 * 4 + 3] = vb.w;
    Ws[r1][kc1 * 4 + 0] = wa.x; Ws[r1][kc1 * 4 + 1] = wa.y;
    Ws[r1][kc1 * 4 + 2] = wa.z; Ws[r1][kc1 * 4 + 3] = wa.w;
    Ws[r1 + 32][kc1 * 4 + 0] = wb.x; Ws[r1 + 32][kc1 * 4 + 1] = wb.y;
    Ws[r1 + 32][kc1 * 4 + 2] = wb.z; Ws[r1 + 32][kc1 * 4 + 3] = wb.w;
    __syncthreads();
#pragma unroll
    for (int k = 0; k < 32; ++k) {
      float a_[4], b_[4];
#pragma unroll
      for (int i = 0; i < 4; i++) a_[i] = Xs[ty * 4 + i][k];
#pragma unroll
      for (int q = 0; q < 4; q++) b_[q] = Ws[tx * 4 + q][k];
#pragma unroll
      for (int i = 0; i < 4; i++)
#pragma unroll
        for (int q = 0; q < 4; q++) acc[i][q] = fmaf(a_[i], b_[q], acc[i][q]);
    }
  }

  float4 bias = *(const float4*)&b0ih[c0 + tx * 4];
#pragma unroll
  for (int i = 0; i < 4; i++) {
    int tloc = tt * 64 + ty * 4 + i;
    float4 o;
    o.x = acc[i][0] + bias.x;
    o.y = acc[i][1] + bias.y;
    o.z = acc[i][2] + bias.z;
    o.w = acc[i][3] + bias.w;
    *(float4*)&gi0[((size_t)b * Tc + tloc) * N3 + c0 + tx * 4] = o;
  }

  if (tid < 64) sflag[tid] = 0;
  __syncthreads();
  if (f1) sflag[r1] = 1;
  if (f2) sflag[r1 + 32] = 1;
  __syncthreads();
  if (tid < 64 && sflag[tid]) act[t0 + tt * 64 + tid] = 1;
}

// ---------------- pass 2: sequential scan, one WG (512 thr) per batch row ----------------
// Round-11: ALL 5 weight matrices live in VGPRs as packed f16x2 (15 rows x
// 4 dwords = 60 VGPRs/thread) consumed directly by v_dot2_f32_f16 with f32
// accumulation. Total demand ~115 regs < the 128 cap at 2 waves/SIMD, so
// residency needs no allocator fight (rounds 2-8 lesson: f32's 120-reg set
// NEVER fit). Zero weight LDS/L2 traffic in the loop; only f16 h (16B/read)
// goes through LDS. State h0/h1/h2 stays f32 in registers -- f16 rounding
// enters only as dot inputs, so error doesn't compound across steps.
// Thread (jj = tid>>3, g = tid&7) owns cols [8g,8g+8) of rows {jj,jj+64,
// jj+128}. DPP reduce over g; 2 barriers/step.
// Hoisting discipline (round-5 race lesson): phase-0 may read only
// s_h16[0][cur] and s_h16[1][cur]; s_h16[2][cur]'s dot stays in layer 2.
__global__ __launch_bounds__(512, 2) void scan_kernel(
    const float* __restrict__ gi0,   // [B,Tc,N3]
    const float* __restrict__ w0hh, const float* __restrict__ w1ih,
    const float* __restrict__ w1hh, const float* __restrict__ w2ih,
    const float* __restrict__ w2hh,
    const float* __restrict__ b0hh, const float* __restrict__ b1ih,
    const float* __restrict__ b1hh, const float* __restrict__ b2ih,
    const float* __restrict__ b2hh,
    const int* __restrict__ act,     // [T]
    float* __restrict__ hstate,      // [3,B,H]
    float* __restrict__ out,         // [B,T,H]
    int t0, int Tc) {
  const int b   = blockIdx.x;
  const int tid = threadIdx.x;
  const int jj  = tid >> 3;   // [0,64) hidden unit
  const int g   = tid & 7;    // [0,8) segment

  __shared__ __align__(16) _Float16 s_h16[3][2][H_];  // f16 h for dots
  __shared__ __align__(16) float s_out[32][H_];
  __shared__ int s_act[T_];

  // ---- one-time: load + f16-pack all 15 weight rows into registers ----
  // wpk[m*3+r][c]: m 0=W0hh,1=W1ih,2=W1hh,3=W2ih,4=W2hh; r=gate; c=dword pair
  int wpk[15][4];
  float bs[15];
  {
    const float* wp[5] = {w0hh, w1ih, w1hh, w2ih, w2hh};
    const float* bp[5] = {b0hh, b1ih, b1hh, b2ih, b2hh};
#pragma unroll
    for (int m = 0; m < 5; m++)
#pragma unroll
      for (int r = 0; r < 3; r++) {
        const float* src = wp[m] + (size_t)(jj + 64 * r) * H_ + 8 * g;
        float4 lo = *(const float4*)src;
        float4 hi = *(const float4*)(src + 4);
        h2v p0; p0.x = (_Float16)lo.x; p0.y = (_Float16)lo.y;
        h2v p1; p1.x = (_Float16)lo.z; p1.y = (_Float16)lo.w;
        h2v p2; p2.x = (_Float16)hi.x; p2.y = (_Float16)hi.y;
        h2v p3; p3.x = (_Float16)hi.z; p3.y = (_Float16)hi.w;
        wpk[m * 3 + r][0] = __builtin_bit_cast(int, p0);
        wpk[m * 3 + r][1] = __builtin_bit_cast(int, p1);
        wpk[m * 3 + r][2] = __builtin_bit_cast(int, p2);
        wpk[m * 3 + r][3] = __builtin_bit_cast(int, p3);
        bs[m * 3 + r] = bp[m][jj + 64 * r];
      }
#pragma unroll
    for (int i = 0; i < 15; i++) {
      KEEP(wpk[i][0]); KEEP(wpk[i][1]); KEEP(wpk[i][2]); KEEP(wpk[i][3]);
      KEEP(bs[i]);
    }
  }

  // ---- h state: f32 registers (per jj, replicated over g) + f16 LDS copy ----
  float h0, h1, h2;
  if (t0 == 0) {
    h0 = 0.0f; h1 = 0.0f; h2 = 0.0f;
  } else {
    h0 = hstate[0 * B_ * H_ + b * H_ + jj];
    h1 = hstate[1 * B_ * H_ + b * H_ + jj];
    h2 = hstate[2 * B_ * H_ + b * H_ + jj];
  }
  if (tid < H_) {
    s_h16[0][0][tid] = (_Float16)((t0 == 0) ? 0.0f : hstate[0 * B_ * H_ + b * H_ + tid]);
    s_h16[1][0][tid] = (_Float16)((t0 == 0) ? 0.0f : hstate[1 * B_ * H_ + b * H_ + tid]);
    s_h16[2][0][tid] = (_Float16)((t0 == 0) ? 0.0f : hstate[2 * B_ * H_ + b * H_ + tid]);
  }
  for (int i = tid; i < Tc; i += 512) s_act[i] = act[t0 + i];
  __syncthreads();

  const float* gibase = gi0 + (size_t)b * Tc * N3;
  int cur = 0;
  float giR = gibase[jj], giZ = gibase[jj + 64], giN = gibase[jj + 128];

  // read 8 f16 h values (16B) for this thread's column segment
#define LOADH(dst, layer, par)                                          \
  h2v dst[4];                                                           \
  {                                                                     \
    float4 raw_ = *(const float4*)&s_h16[layer][par][8 * g];            \
    dst[0] = __builtin_bit_cast(h2v, raw_.x);                           \
    dst[1] = __builtin_bit_cast(h2v, raw_.y);                           \
    dst[2] = __builtin_bit_cast(h2v, raw_.z);                           \
    dst[3] = __builtin_bit_cast(h2v, raw_.w);                           \
  }

  for (int t = 0; t < Tc; ++t) {
    // prefetch next step's gi
    int tn = (t + 1 < Tc) ? t + 1 : t;
    const float* gin = gibase + (size_t)tn * N3;
    float nR = gin[jj], nZ = gin[jj + 64], nN = gin[jj + 128];

    const bool a = (s_act[t] != 0);

    // ---- phase 0: hh-dots for layers 0 and 1 (both barrier-protected) ----
    LOADH(ha, 0, cur);
    LOADH(hc, 1, cur);
    float dR = red8(dot8pk(wpk[0], ha)) + bs[0];
    float dZ = red8(dot8pk(wpk[1], ha)) + bs[1];
    float dN = red8(dot8pk(wpk[2], ha)) + bs[2];
    float hR1 = red8(dot8pk(wpk[6], hc)) + bs[6];
    float hZ1 = red8(dot8pk(wpk[7], hc)) + bs[7];
    float hN1 = red8(dot8pk(wpk[8], hc)) + bs[8];

    // ---- gate 0 ----
    {
      float r = sigm_f(giR + dR);
      float z = sigm_f(giZ + dZ);
      float n = tanh_f(giN + r * dN);
      float hn = (1.0f - z) * n + z * h0;
      h0 = a ? hn : h0;
    }
    if (g == 0) s_h16[0][cur ^ 1][jj] = (_Float16)h0;
    __syncthreads();

    // ---- layer 1: gi = W1ih @ h0new ; gate 1 ----
    {
      LOADH(he, 0, cur ^ 1);
      float iR = red8(dot8pk(wpk[3], he)) + bs[3];
      float iZ = red8(dot8pk(wpk[4], he)) + bs[4];
      float iN = red8(dot8pk(wpk[5], he)) + bs[5];
      float r = sigm_f(iR + hR1);
      float z = sigm_f(iZ + hZ1);
      float n = tanh_f(iN + r * hN1);
      float hn = (1.0f - z) * n + z * h1;
      h1 = a ? hn : h1;
    }
    if (g == 0) s_h16[1][cur ^ 1][jj] = (_Float16)h1;
    __syncthreads();

    // ---- layer 2: gi = W2ih @ h1new ; gh = W2hh @ h2 (safe here: two
    //      barriers since s_h16[2][cur] was written) ; gate 2 ----
    {
      LOADH(hf, 1, cur ^ 1);
      LOADH(hg, 2, cur);
      float jR = red8(dot8pk(wpk[9], hf)) + bs[9];
      float jZ = red8(dot8pk(wpk[10], hf)) + bs[10];
      float jN = red8(dot8pk(wpk[11], hf)) + bs[11];
      float kR = red8(dot8pk(wpk[12], hg)) + bs[12];
      float kZ = red8(dot8pk(wpk[13], hg)) + bs[13];
      float kN = red8(dot8pk(wpk[14], hg)) + bs[14];
      float r = sigm_f(jR + kR);
      float z = sigm_f(jZ + kZ);
      float n = tanh_f(jN + r * kN);
      float hn = (1.0f - z) * n + z * h2;
      h2 = a ? hn : h2;
    }
    if (g == 0) {
      s_h16[2][cur ^ 1][jj] = (_Float16)h2;
      s_out[t & 31][jj] = a ? h2 : 0.0f;
    }
    // no barrier needed: s_h16[2][cur^1] is next read in layer 2 of step t+1
    // (behind two barriers); s_h16[0/1] writes are barrier-protected above.
    cur ^= 1;
    giR = nR; giZ = nZ; giN = nN;

    if ((t & 31) == 31) {            // coalesced output flush (Tc % 32 == 0)
      __syncthreads();
      int row = tid >> 4, c4 = (tid & 15) * 4;
      *(float4*)&out[((size_t)b * T_ + t0 + (t - 31) + row) * H_ + c4] =
          *(const float4*)&s_out[row][c4];
      // next s_out write happens after the next step's barriers -> safe
    }
  }
#undef LOADH

  if (g == 0) {
    hstate[0 * B_ * H_ + b * H_ + jj] = h0;
    hstate[1 * B_ * H_ + b * H_ + jj] = h1;
    hstate[2 * B_ * H_ + b * H_ + jj] = h2;
  }
}

extern "C" void kernel_launch(void* const* d_in, const int* in_sizes, int n_in,
                              void* d_out, int out_size, void* d_ws, size_t ws_size,
                              hipStream_t stream) {
  const float* x    = (const float*)d_in[0];
  const float* w0ih = (const float*)d_in[1];
  const float* w0hh = (const float*)d_in[2];
  const float* b0ih = (const float*)d_in[3];
  const float* b0hh = (const float*)d_in[4];
  const float* w1ih = (const float*)d_in[5];
  const float* w1hh = (const float*)d_in[6];
  const float* b1ih = (const float*)d_in[7];
  const float* b1hh = (const float*)d_in[8];
  const float* w2ih = (const float*)d_in[9];
  const float* w2hh = (const float*)d_in[10];
  const float* b2ih = (const float*)d_in[11];
  const float* b2hh = (const float*)d_in[12];
  float* out = (float*)d_out;

  char* p = (char*)d_ws;
  int* act      = (int*)p;    p += 4096;
  float* hstate = (float*)p;  p += (size_t)3 * B_ * H_ * 4;
  size_t fixed = (size_t)(p - (char*)d_ws);

  int Tc = T_;
  while (Tc > 64 && fixed + (size_t)B_ * Tc * N3 * 4 > ws_size) Tc >>= 1;
  float* gi0 = (float*)p;

  hipMemsetAsync(act, 0, T_ * sizeof(int), stream);
  for (int t0 = 0; t0 < T_; t0 += Tc) {
    gemm_kernel<<<dim3(B_ * (Tc / 64), 3), 256, 0, stream>>>(
        x, w0ih, b0ih, gi0, act, t0, Tc);
    scan_kernel<<<B_, 512, 0, stream>>>(
        gi0, w0hh, w1ih, w1hh, w2ih, w2hh,
        b0hh, b1ih, b1hh, b2ih, b2hh, act, hstate, out, t0, Tc);
  }
}